// Round 10
// baseline (805.211 us; speedup 1.0000x reference)
//
#include <hip/hip_runtime.h>
#include <hip/hip_cooperative_groups.h>
#include <cstdint>
#include <cstddef>

namespace cg = cooperative_groups;

// Problem: B=128, L=196, E=2048, D=1024, A=1024, all fp32.
//   dec_q = dh @ Wd^T + bd            (P1 gemm + P2 reduce)
//   u     = dec_q @ Wq                (P3 gemm + P4 reduce)
//   c[b]  = bq . dec_q[b]             (in P5, per-wave)
//   energy= tanh(x.u + c); softmax    (P5; tanh-bounded -> no max needed)
//   y     = softmax-weighted sum of x (P5 per-wave partials + P6 merge)
//   out   = y @ Wv^T + bv             (P7 gemm + P8 reduce)
//
// Round-10: resubmission of round-9 (never acquired a GPU). Round-8's
// cooperative launch produced all-zero output (absmax 0.396 == max|ref|):
// LDS was 32,800 B -> 2 blocks/CU needs 65,600 B, 64 B over the 64 KB
// occupancy pool -> launch rejected, error unchecked. Fixes: (1) LDS =
// GEMM staging only (25.6 KB; attn phase writes per-wave register
// partials straight to Yp, no LDS block-reduce); (2) check the launch
// return code, fall back to the measured-good multi-kernel path;
// (3) Yp aliases part (disjoint live ranges).

struct SmGemm { float As[32][132]; float Bs[32][68]; };  // 25.6 KB

// Split-K GEMM partial for M=128: part[z][m][n] = sum_{k in z-chunk} A[m,k]*B(k,n).
// B: BNC ? [K][N] : [N][K]. Tile 128x64, 4x8 per thread, 256 threads.
template <bool BNC>
__device__ __forceinline__ void gemm_body(
    const float* __restrict__ A, const float* __restrict__ Bm,
    float* __restrict__ part, int N, int K, int kPerZ, int n0, int z,
    SmGemm* sm, int t) {
  const int tx = t & 7, ty = t >> 3;
  const int k0 = z * kPerZ;
  float acc[4][8];
#pragma unroll
  for (int i = 0; i < 4; ++i)
#pragma unroll
    for (int j = 0; j < 8; ++j) acc[i][j] = 0.f;

  for (int kb = k0; kb < k0 + kPerZ; kb += 32) {
    __syncthreads();
    {  // stage A: 128 m x 32 k, transposed into As[kk][m]
      int m = t >> 1, kq = (t & 1) * 16;
      const float* src = A + (size_t)m * K + (kb + kq);
      float4 v0 = *(const float4*)(src + 0);
      float4 v1 = *(const float4*)(src + 4);
      float4 v2 = *(const float4*)(src + 8);
      float4 v3 = *(const float4*)(src + 12);
      sm->As[kq + 0][m] = v0.x; sm->As[kq + 1][m] = v0.y; sm->As[kq + 2][m] = v0.z; sm->As[kq + 3][m] = v0.w;
      sm->As[kq + 4][m] = v1.x; sm->As[kq + 5][m] = v1.y; sm->As[kq + 6][m] = v1.z; sm->As[kq + 7][m] = v1.w;
      sm->As[kq + 8][m] = v2.x; sm->As[kq + 9][m] = v2.y; sm->As[kq + 10][m] = v2.z; sm->As[kq + 11][m] = v2.w;
      sm->As[kq + 12][m] = v3.x; sm->As[kq + 13][m] = v3.y; sm->As[kq + 14][m] = v3.z; sm->As[kq + 15][m] = v3.w;
    }
    if (BNC) {  // B[K][N]: direct row copy, 32 kk x 64 n
      int kk = t >> 3, nq = (t & 7) * 8;
      const float* src = Bm + (size_t)(kb + kk) * N + (n0 + nq);
      float4 v0 = *(const float4*)(src + 0);
      float4 v1 = *(const float4*)(src + 4);
      *(float4*)&sm->Bs[kk][nq + 0] = v0;
      *(float4*)&sm->Bs[kk][nq + 4] = v1;
    } else {  // B[N][K]: transpose, 64 n x 32 k
      int n = t >> 2, kq = (t & 3) * 8;
      const float* src = Bm + (size_t)(n0 + n) * K + (kb + kq);
      float4 v0 = *(const float4*)(src + 0);
      float4 v1 = *(const float4*)(src + 4);
      sm->Bs[kq + 0][n] = v0.x; sm->Bs[kq + 1][n] = v0.y; sm->Bs[kq + 2][n] = v0.z; sm->Bs[kq + 3][n] = v0.w;
      sm->Bs[kq + 4][n] = v1.x; sm->Bs[kq + 5][n] = v1.y; sm->Bs[kq + 6][n] = v1.z; sm->Bs[kq + 7][n] = v1.w;
    }
    __syncthreads();
#pragma unroll 4
    for (int kk = 0; kk < 32; ++kk) {
      float av[4], bv[8];
      *(float4*)&av[0] = *(const float4*)&sm->As[kk][ty * 4];
      *(float4*)&bv[0] = *(const float4*)&sm->Bs[kk][tx * 8 + 0];
      *(float4*)&bv[4] = *(const float4*)&sm->Bs[kk][tx * 8 + 4];
#pragma unroll
      for (int i = 0; i < 4; ++i)
#pragma unroll
        for (int j = 0; j < 8; ++j) acc[i][j] = fmaf(av[i], bv[j], acc[i][j]);
    }
  }
  float* dst = part + (size_t)z * 128 * N;
#pragma unroll
  for (int i = 0; i < 4; ++i) {
    int m = ty * 4 + i;
    float4 lo = make_float4(acc[i][0], acc[i][1], acc[i][2], acc[i][3]);
    float4 hi = make_float4(acc[i][4], acc[i][5], acc[i][6], acc[i][7]);
    *(float4*)&dst[(size_t)m * N + n0 + tx * 8 + 0] = lo;
    *(float4*)&dst[(size_t)m * N + n0 + tx * 8 + 4] = hi;
  }
}

__device__ __forceinline__ void reduce_body(
    const float* __restrict__ part, const float* __restrict__ bias,
    float* __restrict__ outp, int MN, int N, int Z, int gtid) {
  if (gtid * 4 < MN) {
    float4 a = make_float4(0.f, 0.f, 0.f, 0.f);
    for (int z = 0; z < Z; ++z) {
      float4 v = *(const float4*)&part[(size_t)z * MN + gtid * 4];
      a.x += v.x; a.y += v.y; a.z += v.z; a.w += v.w;
    }
    if (bias) {
      int n = (gtid * 4) % N;
      float4 bb = *(const float4*)&bias[n];
      a.x += bb.x; a.y += bb.y; a.z += bb.z; a.w += bb.w;
    }
    *(float4*)&outp[(size_t)gtid * 4] = a;
  }
}

// Streaming pass over x; tanh-bounded energies -> exp without max. Each of
// the 4 waves writes its private register partial to Yp[bid*4+w] (no LDS).
__device__ __forceinline__ void attn_body(
    const float* __restrict__ x, const float* __restrict__ u,
    const float* __restrict__ dec_q, const float* __restrict__ bq,
    float* __restrict__ Yp, float* __restrict__ ss, int bid, int t) {
  const int L = 196, E = 2048, A = 1024, RPB = 49;
  const int lane = t & 63, w = t >> 6;
  const int b = bid >> 2, q = bid & 3;
  const int l0 = q * RPB;

  // c[b] = bq . dec_q[b]  (wave-redundant, shuffle-only)
  const float* dq = dec_q + (size_t)b * A;
  float cB = 0.f;
#pragma unroll
  for (int j = 0; j < 16; ++j) cB = fmaf(bq[lane + j * 64], dq[lane + j * 64], cB);
  for (int off = 32; off; off >>= 1) cB += __shfl_xor(cB, off);

  float4 ur[8];
  const float* ub = u + (size_t)b * E;
#pragma unroll
  for (int i = 0; i < 8; ++i) ur[i] = *(const float4*)(ub + lane * 4 + i * 256);

  float4 ya[8];
#pragma unroll
  for (int i = 0; i < 8; ++i) ya[i] = make_float4(0.f, 0.f, 0.f, 0.f);
  float s = 0.f;

  for (int l = l0 + w; l < l0 + RPB; l += 4) {  // wave-private, no barriers
    const float* xr = x + ((size_t)b * L + l) * E;
    float4 xv[8];
#pragma unroll
    for (int i = 0; i < 8; ++i) xv[i] = *(const float4*)(xr + lane * 4 + i * 256);
    float d = 0.f;
#pragma unroll
    for (int i = 0; i < 8; ++i) {
      d = fmaf(xv[i].x, ur[i].x, d);
      d = fmaf(xv[i].y, ur[i].y, d);
      d = fmaf(xv[i].z, ur[i].z, d);
      d = fmaf(xv[i].w, ur[i].w, d);
    }
    for (int off = 32; off; off >>= 1) d += __shfl_xor(d, off);
    float wj = __expf(tanhf(d + cB));  // energy in [-1,1] -> no max needed
    s += wj;
#pragma unroll
    for (int i = 0; i < 8; ++i) {
      ya[i].x = fmaf(wj, xv[i].x, ya[i].x);
      ya[i].y = fmaf(wj, xv[i].y, ya[i].y);
      ya[i].z = fmaf(wj, xv[i].z, ya[i].z);
      ya[i].w = fmaf(wj, xv[i].w, ya[i].w);
    }
  }
#pragma unroll
  for (int i = 0; i < 8; ++i)
    *(float4*)&Yp[(size_t)(bid * 4 + w) * E + lane * 4 + i * 256] = ya[i];
  if (lane == 0) ss[bid * 4 + w] = s;
}

// Merge 16 per-wave partials per b -> y[b].
__device__ __forceinline__ void merge_body(
    const float* __restrict__ Yp, const float* __restrict__ ss,
    float* __restrict__ y, int b, int t) {
  const int E = 2048;
  float S = 0.f;
#pragma unroll
  for (int p = 0; p < 16; ++p) S += ss[b * 16 + p];
  float inv = 1.f / S;
#pragma unroll
  for (int h = 0; h < 2; ++h) {
    int pos = t * 4 + h * 1024;
    float4 a = make_float4(0.f, 0.f, 0.f, 0.f);
#pragma unroll
    for (int p = 0; p < 16; ++p) {
      float4 v = *(const float4*)&Yp[(size_t)(b * 16 + p) * E + pos];
      a.x += v.x; a.y += v.y; a.z += v.z; a.w += v.w;
    }
    a.x *= inv; a.y *= inv; a.z *= inv; a.w *= inv;
    *(float4*)&y[(size_t)b * E + pos] = a;
  }
}

__global__ __launch_bounds__(256, 2) void fused_attn(
    const float* __restrict__ x,  const float* __restrict__ dh,
    const float* __restrict__ Wq, const float* __restrict__ bq,
    const float* __restrict__ Wv, const float* __restrict__ bv,
    const float* __restrict__ Wd, const float* __restrict__ bd,
    float* __restrict__ out,
    float* __restrict__ dec_q, float* __restrict__ u, float* __restrict__ y,
    float* __restrict__ Yp, float* __restrict__ ss, float* __restrict__ part) {
  cg::grid_group grid = cg::this_grid();
  __shared__ SmGemm smg;  // 25.6 KB -> 2 blocks/CU fits the 64 KB pool
  const int t = threadIdx.x;
  const int bid = blockIdx.x;
  const int gtid = bid * 256 + t;

  // P1: dec_q partials = dh @ Wd^T   (N=1024, K=1024, 16 nblk x Z=32)
  gemm_body<false>(dh, Wd, part, 1024, 1024, 32, (bid & 15) * 64, bid >> 4, &smg, t);
  grid.sync();
  // P2: dec_q = sum_z + bd
  reduce_body(part, bd, dec_q, 131072, 1024, 32, gtid);
  grid.sync();
  // P3: u partials = dec_q @ Wq     (N=2048, K=1024, 32 nblk x Z=16)
  gemm_body<true>(dec_q, Wq, part, 2048, 1024, 64, (bid & 31) * 64, bid >> 5, &smg, t);
  grid.sync();
  // P4: u = sum_z
  reduce_body(part, nullptr, u, 262144, 2048, 16, gtid);
  grid.sync();
  // P5: streaming x pass (Yp aliases part: part is dead here)
  attn_body(x, u, dec_q, bq, Yp, ss, bid, t);
  grid.sync();
  // P6: merge 16 partials -> y
  if (bid < 128) merge_body(Yp, ss, y, bid, t);
  grid.sync();
  // P7: out partials = y @ Wv^T     (N=1024, K=2048, 16 nblk x Z=32)
  gemm_body<false>(y, Wv, part, 1024, 2048, 64, (bid & 15) * 64, bid >> 4, &smg, t);
  grid.sync();
  // P8: out = sum_z + bv
  reduce_body(part, bv, out, 131072, 1024, 32, gtid);
}

// ---- fallback multi-kernel path (same bodies) ----
template <bool BNC>
__global__ __launch_bounds__(256) void k_gemm(
    const float* __restrict__ A, const float* __restrict__ Bm,
    float* __restrict__ part, int N, int K, int kPerZ) {
  __shared__ SmGemm smg;
  gemm_body<BNC>(A, Bm, part, N, K, kPerZ, blockIdx.x * 64, blockIdx.z, &smg,
                 threadIdx.x);
}
__global__ __launch_bounds__(256) void k_reduce(
    const float* __restrict__ part, const float* __restrict__ bias,
    float* __restrict__ outp, int MN, int N, int Z) {
  reduce_body(part, bias, outp, MN, N, Z, blockIdx.x * 256 + threadIdx.x);
}
__global__ __launch_bounds__(256) void k_attn(
    const float* __restrict__ x, const float* __restrict__ u,
    const float* __restrict__ dec_q, const float* __restrict__ bq,
    float* __restrict__ Yp, float* __restrict__ ss) {
  attn_body(x, u, dec_q, bq, Yp, ss, blockIdx.x, threadIdx.x);
}
__global__ __launch_bounds__(256) void k_merge(
    const float* __restrict__ Yp, const float* __restrict__ ss,
    float* __restrict__ y) {
  merge_body(Yp, ss, y, blockIdx.x, threadIdx.x);
}

extern "C" void kernel_launch(void* const* d_in, const int* in_sizes, int n_in,
                              void* d_out, int out_size, void* d_ws, size_t ws_size,
                              hipStream_t stream) {
  const float* x  = (const float*)d_in[0];  // [128,196,2048]
  const float* dh = (const float*)d_in[1];  // [128,1024]
  const float* Wq = (const float*)d_in[2];  // [1024,2048]
  const float* bq = (const float*)d_in[3];  // [1024]
  const float* Wv = (const float*)d_in[4];  // [1024,2048]
  const float* bv = (const float*)d_in[5];  // [1024]
  const float* Wd = (const float*)d_in[6];  // [1024,1024]
  const float* bd = (const float*)d_in[7];  // [1024]
  float* out = (float*)d_out;               // [128,1024]
  float* ws = (float*)d_ws;

  float* dec_q = ws;            // 131072 floats (0.5 MB)
  float* u     = ws + 131072;   // 262144 (1 MB)
  float* y     = ws + 393216;   // 262144 (1 MB)
  float* ssb   = ws + 655360;   // 2048
  float* part  = ws + 657408;   // 4194304 floats (16 MB)
  float* Yp    = part;          // alias: disjoint live ranges
  // total ~18.5 MB of d_ws

  void* args[] = {
      (void*)&x,  (void*)&dh, (void*)&Wq, (void*)&bq, (void*)&Wv, (void*)&bv,
      (void*)&Wd, (void*)&bd, (void*)&out,
      (void*)&dec_q, (void*)&u, (void*)&y, (void*)&Yp, (void*)&ssb, (void*)&part};
  hipError_t err = hipLaunchCooperativeKernel((void*)fused_attn, dim3(512),
                                              dim3(256), args, 0, stream);
  if (err != hipSuccess) {
    // Fallback: measured-good multi-kernel path (round-6 structure).
    k_gemm<false><<<dim3(16, 1, 32), 256, 0, stream>>>(dh, Wd, part, 1024, 1024, 32);
    k_reduce<<<dim3(128), 256, 0, stream>>>(part, bd, dec_q, 131072, 1024, 32);
    k_gemm<true><<<dim3(32, 1, 16), 256, 0, stream>>>(dec_q, Wq, part, 2048, 1024, 64);
    k_reduce<<<dim3(256), 256, 0, stream>>>(part, nullptr, u, 262144, 2048, 16);
    k_attn<<<dim3(512), 256, 0, stream>>>(x, u, dec_q, bq, Yp, ssb);
    k_merge<<<dim3(128), 256, 0, stream>>>(Yp, ssb, y);
    k_gemm<false><<<dim3(16, 1, 32), 256, 0, stream>>>(y, Wv, part, 1024, 2048, 64);
    k_reduce<<<dim3(128), 256, 0, stream>>>(part, bv, out, 131072, 1024, 32);
  }
}